// Round 8
// baseline (562.389 us; speedup 1.0000x reference)
//
#include <hip/hip_runtime.h>

typedef float f4 __attribute__((ext_vector_type(4)));
typedef short s4 __attribute__((ext_vector_type(4)));
typedef short s8 __attribute__((ext_vector_type(8)));
typedef unsigned short u16x4 __attribute__((ext_vector_type(4)));

// ---- ws layout (bytes) ----
// embB   : 1 MiB    .. 5 MiB   (4096*512 bf16)
// rbC    : 5 MiB    .. 37 MiB  (64*512*512 bf16, [n][i][o] — SAME layout as input, just bf16)
// gemmT  : 37 MiB   .. 53 MiB  (2 slices of 4096*512 f32, [b][o])

__device__ __forceinline__ unsigned short f2bf(float f) {
    unsigned int u = __float_as_uint(f);
    unsigned int r = (u + 0x7fffu + ((u >> 16) & 1u)) >> 16;
    return (unsigned short)r;
}

// prep v8: PURE STREAMING CASTS — no transpose, no LDS, no barriers.
// blocks [0,2048): emb f32->bf16 (1 f4/thread).
// blocks [2048,6144): rb cast, 1024 f4-granules per block (R7 had b2*4096 indexing:
// 4x OOB -> workspace corruption -> core dump. Fixed: b2*1024 + k*256 + t).
__global__ __launch_bounds__(256) void prep_kernel(const float* __restrict__ emb,
                                                   unsigned short* __restrict__ embB,
                                                   const float* __restrict__ rb,
                                                   unsigned short* __restrict__ rbC) {
    int bid = blockIdx.x;
    int t = threadIdx.x;
    if (bid < 2048) {
        int g = (bid * 256 + t) * 4;
        f4 v = *(const f4*)(emb + g);
        u16x4 o;
        o[0] = f2bf(v[0]); o[1] = f2bf(v[1]); o[2] = f2bf(v[2]); o[3] = f2bf(v[3]);
        *(u16x4*)(embB + g) = o;
        return;
    }
    size_t b2 = bid - 2048;
#pragma unroll
    for (int k = 0; k < 4; k++) {
        size_t idx = b2 * 1024 + (size_t)k * 256 + t;     // f4-granule index, total 4096*1024
        f4 v = *(const f4*)(rb + idx * 4);
        u16x4 o;
        o[0] = f2bf(v[0]); o[1] = f2bf(v[1]); o[2] = f2bf(v[2]); o[3] = f2bf(v[3]);
        *(u16x4*)(rbC + idx * 4) = o;
    }
}

// Main fused GEMM v8 — OPERAND SWAP: D[b][o] = A(emb[b][i]) x B(rel_base[n][i][o]).
// - embF fragments: byte-identical to champion (A/B lane-layout duality) — A operand now.
// - B fragments: ds_read_b64_tr_b16. Lane addressing per m156/m162: the 16-lane
//   group must supply tile_base + (lane&15)*8 BYTES (each lane owns an 8B slot of
//   the 128B 4x16 tile; crossbar returns column lane&15). R7 had lm*2 — wrong.
// - Staging: champion's global_load_lds distance-2 dbuf, vmcnt(4)/lgkmcnt(0); panel
//   layout encoded in PER-LANE GLOBAL src addresses, LDS dest linear (rule #21).
// - No setprio (R4/R5 evidence). No epilogue transpose (stores are [b][o] direct).
// - Rule #18: lgkmcnt(0) + sched_barrier(0) after asm tr-reads, before re-stage.
// LDS = 2x16KB dbuf + 8KB attS = 40960 (same as champion).
__global__ __launch_bounds__(256, 4) void gemm_fold(const unsigned short* __restrict__ embB,
                                                    const unsigned short* __restrict__ rbC,
                                                    const int* __restrict__ ids,
                                                    const float* __restrict__ rel_att,
                                                    const float* __restrict__ relb,
                                                    float* __restrict__ gemmT) {
    __shared__ unsigned short bS[2][8192];        // [buf][panel wv][i 128][oo 16] bf16
    __shared__ float attS[32][64];                // [n][b] broadcast layout

    const int t = threadIdx.x;
    const int wv = t >> 6;
    const int ln = t & 63;
    const int q  = ln >> 4;     // quad 0..3
    const int lm = ln & 15;
    const int g  = blockIdx.x;
    const int o0 = (g & 7) * 64;                  // fastest -> XCD-aligned o slice
    const int m0 = ((g >> 3) & 63) * 64;
    const int nz = g >> 9;                        // n-half 0/1
    const int nbase = nz * 32;

    // stage one (n, ic) tile: [128 i][64 o] as 4 o-panels of [128 i][16 oo].
    // wave wv stages its OWN panel (4 chunks x 1KB); lane l in chunk j covers
    // (i = j*32 + l/2, oo = (l&1)*8) -> per-lane global src, linear LDS dest.
    auto stage = [&](int s, int buf) {
        const int ic = s >> 5, n = nbase + (s & 31);
        const unsigned short* gb = rbC + (size_t)n * 262144 + (size_t)(ic * 128) * 512
                                 + o0 + wv * 16 + (ln & 1) * 8;
        const int irow = ln >> 1;
#pragma unroll
        for (int j = 0; j < 4; j++) {
            const unsigned short* gp = gb + (size_t)(j * 32 + irow) * 512;
            void* l = (char*)(&bS[buf][0]) + wv * 4096 + j * 1024;
            __builtin_amdgcn_global_load_lds((const __attribute__((address_space(1))) void*)gp,
                                             (__attribute__((address_space(3))) void*)l,
                                             16, 0, 0);
        }
    };

    stage(0, 0);
    stage(1, 1);

    // att tile [32 n][64 b], gathered via ids: 8 per thread
#pragma unroll
    for (int k = 0; k < 8; k++) {
        int idx = t + 256 * k;
        int n = idx >> 6, m = idx & 63;
        attS[n][m] = rel_att[(size_t)ids[m0 + m] * 64 + nbase + n];
    }
    __syncthreads();                              // the ONLY block barrier

    const f4 z = {0.f, 0.f, 0.f, 0.f};
    f4 acc[4] = {z, z, z, z};
    s8 embF[4][4];

    // tr-read base: panel wv; tile at i0 = ks*32 + q*8 -> byte ks*1024 + q*256;
    // lane slot = lm*8 bytes (m156 pattern). offset:128 = +4 i-rows.
    const int trb = wv * 4096 + q * 256 + lm * 8;

    for (int s = 0; s < 128; s++) {
        int nl = s & 31;
        // tile s landed when only tile s+1's 4 loads remain outstanding
        if (s < 127) asm volatile("s_waitcnt vmcnt(4)" ::: "memory");
        else         asm volatile("s_waitcnt vmcnt(0)" ::: "memory");

        if (nl == 0) {
            // emb fragments (A operand) for this i-chunk: same bytes as champion.
            int ic = s >> 5;
#pragma unroll
            for (int ks = 0; ks < 4; ks++)
#pragma unroll
                for (int ms = 0; ms < 4; ms++)
                    embF[ks][ms] = *(const s8*)(embB + (size_t)(m0 + ms * 16 + lm) * 512
                                                + ic * 128 + ks * 32 + q * 8);
        }

        // B fragments: 8 x ds_read_b64_tr_b16 -> bF[ks][j] = B[i=ks*32+q*8+j][oo=lm]
        const int ab = (s & 1) * 16384 + trb;
        s8 bF[4];
#pragma unroll
        for (int ks = 0; ks < 4; ks++) {
            int a = ab + ks * 1024;
            s4 lo, hi;
            asm volatile("ds_read_b64_tr_b16 %0, %1" : "=&v"(lo) : "v"(a));
            asm volatile("ds_read_b64_tr_b16 %0, %1 offset:128" : "=&v"(hi) : "v"(a));
            bF[ks] = __builtin_shufflevector(lo, hi, 0, 1, 2, 3, 4, 5, 6, 7);
        }
        // att row-scales: av4[ms][r] = att[n=nl][b = ms*16 + q*4 + r] (broadcast b128)
        f4 av4[4];
#pragma unroll
        for (int ms = 0; ms < 4; ms++)
            av4[ms] = *(const f4*)(&attS[nl][ms * 16 + q * 4]);

        // all LDS reads complete; pin so MFMAs can't hoist above (rule #18), then
        // re-stage this buffer (WAR resolved).
        asm volatile("s_waitcnt lgkmcnt(0)" ::: "memory");
        __builtin_amdgcn_sched_barrier(0);
        if (s + 2 < 128) stage(s + 2, s & 1);

        f4 an[4];
#pragma unroll
        for (int ms = 0; ms < 4; ms++)
            an[ms] = __builtin_amdgcn_mfma_f32_16x16x32_bf16(embF[0][ms], bF[0], z, 0, 0, 0);
#pragma unroll
        for (int ks = 1; ks < 4; ks++)
#pragma unroll
            for (int ms = 0; ms < 4; ms++)
                an[ms] = __builtin_amdgcn_mfma_f32_16x16x32_bf16(embF[ks][ms], bF[ks], an[ms], 0, 0, 0);
#pragma unroll
        for (int ms = 0; ms < 4; ms++)
            acc[ms] += av4[ms] * an[ms];
    }

    // bias fold: acc[ms][r] += sum_n att[n][b(ms,r)] * relb[nbase+n][o]
    const int o = o0 + wv * 16 + lm;
    const float* rbp = relb + (size_t)nbase * 512 + o;
#pragma unroll 4
    for (int n = 0; n < 32; n++) {
        float rv = rbp[(size_t)n * 512];          // coalesced over lm; scalar per lane
#pragma unroll
        for (int ms = 0; ms < 4; ms++)
            acc[ms] += (*(const f4*)(&attS[n][ms * 16 + q * 4])) * rv;
    }

    // direct [b][o] store — no transpose, no barriers: D row = b, col = o.
    float* gB = gemmT + (size_t)nz * 4096 * 512;
#pragma unroll
    for (int ms = 0; ms < 4; ms++)
#pragma unroll
        for (int r = 0; r < 4; r++)
            gB[(size_t)(m0 + ms * 16 + q * 4 + r) * 512 + o] = acc[ms][r];
}

// LayerNorm over o (512) per b, [b][o] layout: pure-register, no LDS.
// 4 rows per block (64 lanes/row, wave-wide shuffle reduce); grid 1024.
__global__ __launch_bounds__(256) void ln_kernel(const float* __restrict__ g0,
                                                 const float* __restrict__ g1,
                                                 float* __restrict__ out) {
    int t = threadIdx.x;
    int b = blockIdx.x * 4 + (t >> 6);
    int l = t & 63;
    const float* p0 = g0 + (size_t)b * 512 + l * 4;
    const float* p1 = g1 + (size_t)b * 512 + l * 4;
    f4 v[2];
    float s1 = 0.f, s2 = 0.f;
#pragma unroll
    for (int j = 0; j < 2; j++) {
        f4 a = *(const f4*)(p0 + j * 256);
        f4 c = *(const f4*)(p1 + j * 256);
        f4 w = a + c;
        v[j] = w;
        s1 += w[0] + w[1] + w[2] + w[3];
        s2 += w[0] * w[0] + w[1] * w[1] + w[2] * w[2] + w[3] * w[3];
    }
#pragma unroll
    for (int off = 32; off; off >>= 1) {
        s1 += __shfl_xor(s1, off, 64);
        s2 += __shfl_xor(s2, off, 64);
    }
    float mu = s1 * (1.f / 512.f);
    float var = s2 * (1.f / 512.f) - mu * mu;
    float rs = rsqrtf(var + 1e-5f);
    float* po = out + (size_t)b * 512 + l * 4;
#pragma unroll
    for (int j = 0; j < 2; j++) {
        f4 w = (v[j] - mu) * rs;
        *(f4*)(po + j * 256) = w;
    }
}

extern "C" void kernel_launch(void* const* d_in, const int* in_sizes, int n_in,
                              void* d_out, int out_size, void* d_ws, size_t ws_size,
                              hipStream_t stream) {
    (void)in_sizes; (void)n_in; (void)out_size; (void)ws_size;
    const float* emb      = (const float*)d_in[0];
    const int*   proj_ids = (const int*)d_in[1];
    const float* rel_att  = (const float*)d_in[2];
    const float* rel_base = (const float*)d_in[3];
    const float* rel_bias = (const float*)d_in[4];
    float* out = (float*)d_out;

    char* w = (char*)d_ws;
    unsigned short* embB  = (unsigned short*)(w + (1u << 20));
    unsigned short* rbC   = (unsigned short*)(w + 5u * (1u << 20));
    float*          gemmT = (float*)(w + 37u * (1u << 20));   // 2 slices of 8 MiB, [b][o]
    float*          g1    = gemmT + (size_t)4096 * 512;

    prep_kernel<<<dim3(2048 + 4096), dim3(256), 0, stream>>>(emb, embB, rel_base, rbC);
    gemm_fold<<<dim3(1024), dim3(256), 0, stream>>>(embB, rbC, proj_ids, rel_att, rel_bias, gemmT);
    ln_kernel<<<dim3(1024), dim3(256), 0, stream>>>(gemmT, g1, out);
}

// Round 9
// 310.017 us; speedup vs baseline: 1.8141x; 1.8141x over previous
//
#include <hip/hip_runtime.h>

typedef float f4 __attribute__((ext_vector_type(4)));
typedef short s8 __attribute__((ext_vector_type(8)));
typedef unsigned short u16x4 __attribute__((ext_vector_type(4)));
typedef unsigned short u16x8 __attribute__((ext_vector_type(8)));

// ---- ws layout (bytes) ----
// embB   : 1 MiB    .. 5 MiB   (4096*512 bf16)
// rbT    : 5 MiB    .. 37 MiB  (64*512*512 bf16, [n][o][i])
// gemmT  : 37 MiB   .. 53 MiB  (2 slices of 4096*512 f32, [b][o])

__device__ __forceinline__ unsigned short f2bf(float f) {
    unsigned int u = __float_as_uint(f);
    unsigned int r = (u + 0x7fffu + ((u >> 16) & 1u)) >> 16;
    return (unsigned short)r;
}

// blocks [0,1024): rbT transpose, one block per (n, o-tile, i-half); 4 i-tiles each,
// double-buffered LDS. blocks [1024, 3072): emb f32->bf16.  (R5-proven)
__global__ __launch_bounds__(256) void prep_kernel(const float* __restrict__ emb,
                                                   unsigned short* __restrict__ embB,
                                                   const float* __restrict__ rb,
                                                   unsigned short* __restrict__ rbT) {
    int bid = blockIdx.x;
    int t = threadIdx.x;
    if (bid >= 1024) {
        int g = ((bid - 1024) * 256 + t) * 4;
        f4 v = *(const f4*)(emb + g);
        u16x4 o;
        o[0] = f2bf(v[0]); o[1] = f2bf(v[1]); o[2] = f2bf(v[2]); o[3] = f2bf(v[3]);
        *(u16x4*)(embB + g) = o;
        return;
    }
    __shared__ float tl[2][64][65];
    int n = bid >> 4;
    int sub = bid & 15;
    int o0 = (sub & 7) * 64;
    int ibase = (sub >> 3) * 4;            // i-tile range [ibase, ibase+4)
    int oq = t & 15, ir = t >> 4;
    int ic = t & 7, or0 = t >> 3;
    const float* rbn = rb + (size_t)n * 262144;
    unsigned short* rbTn = rbT + (size_t)n * 262144;

    f4 v[4];
#pragma unroll
    for (int k = 0; k < 4; k++)
        v[k] = *(const f4*)(rbn + (size_t)(ibase * 64 + ir + 16 * k) * 512 + o0 + oq * 4);

    for (int jj = 0; jj < 4; jj++) {
        int ii = ibase + jj;
        int buf = jj & 1;
#pragma unroll
        for (int k = 0; k < 4; k++) {
            int r = ir + 16 * k;
            tl[buf][r][oq * 4 + 0] = v[k][0]; tl[buf][r][oq * 4 + 1] = v[k][1];
            tl[buf][r][oq * 4 + 2] = v[k][2]; tl[buf][r][oq * 4 + 3] = v[k][3];
        }
        if (jj < 3) {
            int i0n = (ii + 1) * 64;
#pragma unroll
            for (int k = 0; k < 4; k++)
                v[k] = *(const f4*)(rbn + (size_t)(i0n + ir + 16 * k) * 512 + o0 + oq * 4);
        }
        __syncthreads();
        int i0 = ii * 64;
#pragma unroll
        for (int k = 0; k < 2; k++) {
            int orow = or0 + 32 * k;
            u16x8 w;
#pragma unroll
            for (int j = 0; j < 8; j++) w[j] = f2bf(tl[buf][ic * 8 + j][orow]);
            *(u16x8*)(rbTn + (size_t)(o0 + orow) * 512 + i0 + ic * 8) = w;
        }
    }
}

// Main fused GEMM v9 — 8-wave shared tile (BM=128), 3-buffer distance-2 staging,
// ONE s_barrier per K-step.
// Why: champion (R5, 176us) is LDS-BW-bound at 576 staged+read B per MFMA
// (MfmaUtil pinned 35% across all scheduling variants). Sharing one staged
// [64o x 128i] tile across 8 waves (two m-groups of 64 b) halves staged
// bytes/MFMA. Race safety WITHOUT pinned scheduling:
//  - stage(s+2) -> buf[(s+2)%3] == buf[(s-1)%3]: its readers (iter s-1) were
//    certified done at iter s-1's barrier (lgkmcnt(0) precedes each barrier).
//  - reads of tile s are safe: iter s-1's per-wave vmcnt(2) + barrier certify
//    ALL waves' tile-s chunk loads landed.
// Swizzle identical to champion (row&15 == lm invariant holds: row=wq*16+lm).
// LDS 3x16KB + 16KB attS = 64KB -> 2 blocks/CU = 16 waves/CU; grid 512 = exact fill.
__global__ __launch_bounds__(512, 4) void gemm_fold(const unsigned short* __restrict__ embB,
                                                    const unsigned short* __restrict__ rbT,
                                                    const int* __restrict__ ids,
                                                    const float* __restrict__ rel_att,
                                                    const float* __restrict__ relb,
                                                    float* __restrict__ gemmT) {
    __shared__ unsigned short bS[3][8192];        // [buf][o_local*128 + i_local] (xor-swizzled)
    __shared__ float attS[32][128];               // [n][b_local] broadcast layout

    const int t = threadIdx.x;
    const int w  = t >> 6;                        // wave 0..7
    const int ln = t & 63;
    const int q  = ln >> 4;
    const int lm = ln & 15;
    const int wq = w & 3;                         // o-quarter (rows wq*16..+16)
    const int wg = w >> 2;                        // m-group (b offset wg*64)
    const int g  = blockIdx.x;
    const int o0 = (g & 7) * 64;                  // XCD-aligned o slice
    const int m0 = ((g >> 3) & 31) * 128;
    const int nz = g >> 8;                        // n-half 0/1
    const int nbase = nz * 32;

    // stage one 64o x 128i tile (16 chunks of 1KB); wave w stages chunks 2w,2w+1
    // (rows 8w..8w+7). Same per-lane swizzled global src as champion.
    auto stage = [&](int s, int buf) {
        int ic = s >> 5, n = nbase + (s & 31);
#pragma unroll
        for (int j = 0; j < 2; j++) {
            int c   = w * 2 + j;                  // chunk 0..15
            int r   = c * 4 + q;                  // o_local
            int c16 = lm ^ (r & 15);              // logical i-chunk for this lane's slot
            const unsigned short* gp = rbT + (size_t)(n * 512 + o0 + r) * 512 + ic * 128 + c16 * 8;
            void* l = (char*)(&bS[buf][0]) + c * 1024;
            __builtin_amdgcn_global_load_lds((const __attribute__((address_space(1))) void*)gp,
                                             (__attribute__((address_space(3))) void*)l,
                                             16, 0, 0);
        }
    };

    stage(0, 0);
    stage(1, 1);

    // att tile [32 n][128 b], gathered via ids: 8 per thread
#pragma unroll
    for (int k = 0; k < 8; k++) {
        int idx = t + 512 * k;                    // 0..4095
        int n = idx >> 7, m = idx & 127;
        attS[n][m] = rel_att[(size_t)ids[m0 + m] * 64 + nbase + n];
    }
    __syncthreads();   // drains vmcnt(0) too -> tiles 0 and 1 certified resident

    const f4 z = {0.f, 0.f, 0.f, 0.f};
    f4 acc[4] = {z, z, z, z};
    s8 embF[4][4];

    int rb_ = 0;                                  // s % 3 (read buffer)
    int sb_ = 2;                                  // (s+2) % 3 (stage buffer)

    for (int s = 0; s < 128; s++) {
        int nl = s & 31;
        if (nl == 0) {
            // emb fragments for this i-chunk, this wave's m-group.
            int ic = s >> 5;
#pragma unroll
            for (int ks = 0; ks < 4; ks++)
#pragma unroll
                for (int ms = 0; ms < 4; ms++)
                    embF[ks][ms] = *(const s8*)(embB + (size_t)(m0 + wg * 64 + ms * 16 + lm) * 512
                                                + ic * 128 + ks * 32 + q * 8);
        }

        const unsigned short* bp = &bS[rb_][0];
        s8 aF[4];
#pragma unroll
        for (int ks = 0; ks < 4; ks++) {
            int c16 = (ks * 4 + q) ^ lm;          // un-swizzle (row&15 == lm)
            aF[ks] = *(const s8*)(bp + (wq * 16 + lm) * 128 + c16 * 8);
        }
        // my reads of tile s complete BEFORE the barrier -> any later stage into
        // this buffer (iter s+1's stage(s+3)) cannot corrupt them.
        asm volatile("s_waitcnt lgkmcnt(0)" ::: "memory");
        if (s + 2 < 128) stage(s + 2, sb_);
        // own chunk-loads for tile s+1 landed (embF loads, if any, drain too);
        // tile s+2 (2 loads) stays in flight.
        if (s < 126) asm volatile("s_waitcnt vmcnt(2)" ::: "memory");
        else         asm volatile("s_waitcnt vmcnt(0)" ::: "memory");
        __builtin_amdgcn_s_barrier();             // certify: tile s+1 ready, tile-s reads done

        f4 an[4];
#pragma unroll
        for (int ms = 0; ms < 4; ms++)
            an[ms] = __builtin_amdgcn_mfma_f32_16x16x32_bf16(aF[0], embF[0][ms], z, 0, 0, 0);
#pragma unroll
        for (int ks = 1; ks < 4; ks++)
#pragma unroll
            for (int ms = 0; ms < 4; ms++)
                an[ms] = __builtin_amdgcn_mfma_f32_16x16x32_bf16(aF[ks], embF[ks][ms], an[ms], 0, 0, 0);
#pragma unroll
        for (int ms = 0; ms < 4; ms++) {
            float av = attS[nl][wg * 64 + ms * 16 + lm];
            acc[ms] += av * an[ms];
        }
        rb_ = (rb_ == 2) ? 0 : rb_ + 1;
        sb_ = (sb_ == 2) ? 0 : sb_ + 1;
    }

    // bias fold: acc[ms] += sum_{n in half} att(n, b) * relb[nbase+n][o]
    const float* rbb = relb + (size_t)nbase * 512 + o0 + wq * 16 + q * 4;
#pragma unroll 4
    for (int n = 0; n < 32; n++) {
        f4 rb4 = *(const f4*)(rbb + (size_t)n * 512);
#pragma unroll
        for (int ms = 0; ms < 4; ms++)
            acc[ms] += attS[n][wg * 64 + ms * 16 + lm] * rb4;
    }

    // transpose epilogue: acc -> [b][o] tile via LDS (reuse bS as float[128][68]),
    // then coalesced 64B-per-thread stores.
    __syncthreads();
    float* T = (float*)&bS[0][0];
#pragma unroll
    for (int ms = 0; ms < 4; ms++)
#pragma unroll
        for (int r = 0; r < 4; r++)
            T[(wg * 64 + ms * 16 + lm) * 68 + wq * 16 + q * 4 + r] = acc[ms][r];
    __syncthreads();
    float* gB = gemmT + (size_t)nz * 4096 * 512;
    const int mrow = t >> 2;                      // 0..127
    const int oc = (t & 3) * 16;
    const float* Tr = T + mrow * 68 + oc;
    float* gp = gB + (size_t)(m0 + mrow) * 512 + o0 + oc;
#pragma unroll
    for (int j = 0; j < 4; j++)
        *(f4*)(gp + j * 4) = *(const f4*)(Tr + j * 4);
}

// LayerNorm over o (512) per b, [b][o] layout: pure-register, no LDS.
// 4 rows per block (64 lanes/row); grid 1024.  (R5-proven)
__global__ __launch_bounds__(256) void ln_kernel(const float* __restrict__ g0,
                                                 const float* __restrict__ g1,
                                                 float* __restrict__ out) {
    int t = threadIdx.x;
    int b = blockIdx.x * 4 + (t >> 6);
    int l = t & 63;
    const float* p0 = g0 + (size_t)b * 512 + l * 4;
    const float* p1 = g1 + (size_t)b * 512 + l * 4;
    f4 v[2];
    float s1 = 0.f, s2 = 0.f;
#pragma unroll
    for (int j = 0; j < 2; j++) {
        f4 a = *(const f4*)(p0 + j * 256);
        f4 c = *(const f4*)(p1 + j * 256);
        f4 w = a + c;
        v[j] = w;
        s1 += w[0] + w[1] + w[2] + w[3];
        s2 += w[0] * w[0] + w[1] * w[1] + w[2] * w[2] + w[3] * w[3];
    }
#pragma unroll
    for (int off = 32; off; off >>= 1) {
        s1 += __shfl_xor(s1, off, 64);
        s2 += __shfl_xor(s2, off, 64);
    }
    float mu = s1 * (1.f / 512.f);
    float var = s2 * (1.f / 512.f) - mu * mu;
    float rs = rsqrtf(var + 1e-5f);
    float* po = out + (size_t)b * 512 + l * 4;
#pragma unroll
    for (int j = 0; j < 2; j++) {
        f4 w = (v[j] - mu) * rs;
        *(f4*)(po + j * 256) = w;
    }
}

extern "C" void kernel_launch(void* const* d_in, const int* in_sizes, int n_in,
                              void* d_out, int out_size, void* d_ws, size_t ws_size,
                              hipStream_t stream) {
    (void)in_sizes; (void)n_in; (void)out_size; (void)ws_size;
    const float* emb      = (const float*)d_in[0];
    const int*   proj_ids = (const int*)d_in[1];
    const float* rel_att  = (const float*)d_in[2];
    const float* rel_base = (const float*)d_in[3];
    const float* rel_bias = (const float*)d_in[4];
    float* out = (float*)d_out;

    char* w = (char*)d_ws;
    unsigned short* embB  = (unsigned short*)(w + (1u << 20));
    unsigned short* rbT   = (unsigned short*)(w + 5u * (1u << 20));
    float*          gemmT = (float*)(w + 37u * (1u << 20));   // 2 slices of 8 MiB, [b][o]
    float*          g1    = gemmT + (size_t)4096 * 512;

    prep_kernel<<<dim3(1024 + 2048), dim3(256), 0, stream>>>(emb, embB, rel_base, rbT);
    gemm_fold<<<dim3(512), dim3(512), 0, stream>>>(embB, rbT, proj_ids, rel_att, rel_bias, gemmT);
    ln_kernel<<<dim3(1024), dim3(256), 0, stream>>>(gemmT, g1, out);
}

// Round 10
// 271.657 us; speedup vs baseline: 2.0702x; 1.1412x over previous
//
#include <hip/hip_runtime.h>
#include <hip/hip_fp16.h>

typedef float f4 __attribute__((ext_vector_type(4)));
typedef short s8 __attribute__((ext_vector_type(8)));
typedef unsigned short u16x4 __attribute__((ext_vector_type(4)));
typedef unsigned short u16x8 __attribute__((ext_vector_type(8)));

// ---- ws layout (bytes) ----
// embB   : 1 MiB    .. 5 MiB   (4096*512 bf16)
// rbT    : 5 MiB    .. 37 MiB  (64*512*512 bf16, [n][o][i])
// gemmT  : 37 MiB   .. 53 MiB  (2 slices of 4096*512 f32, [b][o])

__device__ __forceinline__ unsigned short f2bf(float f) {
    unsigned int u = __float_as_uint(f);
    unsigned int r = (u + 0x7fffu + ((u >> 16) & 1u)) >> 16;
    return (unsigned short)r;
}

// blocks [0,1024): rbT transpose, one block per (n, o-tile, i-half); 4 i-tiles each,
// double-buffered LDS. blocks [1024, 3072): emb f32->bf16.  (R5-proven)
__global__ __launch_bounds__(256) void prep_kernel(const float* __restrict__ emb,
                                                   unsigned short* __restrict__ embB,
                                                   const float* __restrict__ rb,
                                                   unsigned short* __restrict__ rbT) {
    int bid = blockIdx.x;
    int t = threadIdx.x;
    if (bid >= 1024) {
        int g = ((bid - 1024) * 256 + t) * 4;
        f4 v = *(const f4*)(emb + g);
        u16x4 o;
        o[0] = f2bf(v[0]); o[1] = f2bf(v[1]); o[2] = f2bf(v[2]); o[3] = f2bf(v[3]);
        *(u16x4*)(embB + g) = o;
        return;
    }
    __shared__ float tl[2][64][65];
    int n = bid >> 4;
    int sub = bid & 15;
    int o0 = (sub & 7) * 64;
    int ibase = (sub >> 3) * 4;            // i-tile range [ibase, ibase+4)
    int oq = t & 15, ir = t >> 4;
    int ic = t & 7, or0 = t >> 3;
    const float* rbn = rb + (size_t)n * 262144;
    unsigned short* rbTn = rbT + (size_t)n * 262144;

    f4 v[4];
#pragma unroll
    for (int k = 0; k < 4; k++)
        v[k] = *(const f4*)(rbn + (size_t)(ibase * 64 + ir + 16 * k) * 512 + o0 + oq * 4);

    for (int jj = 0; jj < 4; jj++) {
        int ii = ibase + jj;
        int buf = jj & 1;
#pragma unroll
        for (int k = 0; k < 4; k++) {
            int r = ir + 16 * k;
            tl[buf][r][oq * 4 + 0] = v[k][0]; tl[buf][r][oq * 4 + 1] = v[k][1];
            tl[buf][r][oq * 4 + 2] = v[k][2]; tl[buf][r][oq * 4 + 3] = v[k][3];
        }
        if (jj < 3) {
            int i0n = (ii + 1) * 64;
#pragma unroll
            for (int k = 0; k < 4; k++)
                v[k] = *(const f4*)(rbn + (size_t)(i0n + ir + 16 * k) * 512 + o0 + oq * 4);
        }
        __syncthreads();
        int i0 = ii * 64;
#pragma unroll
        for (int k = 0; k < 2; k++) {
            int orow = or0 + 32 * k;
            u16x8 w;
#pragma unroll
            for (int j = 0; j < 8; j++) w[j] = f2bf(tl[buf][ic * 8 + j][orow]);
            *(u16x8*)(rbTn + (size_t)(o0 + orow) * 512 + i0 + ic * 8) = w;
        }
    }
}

// Main fused GEMM v10 — the 176us champion body with ONE change: attS f32 (8KB)
// -> attH packed f16 pairs (4KB). LDS 40960 -> 36864: the champion's 40960 was
// exactly 160K/4 and did NOT co-schedule 4 blocks (measured 37% occ = 3/CU).
// 36864 x 4 = 144KB < 160KB -> 4 blocks/CU. Attacks the measured ~26% vmcnt
// stall (R9 refuted pure-LDS-BW: halving staged bytes didn't help).
// f16 att verified numerically safe (R1: same absmax 0.03125).
// NO setprio (R4/R5 A/B). NO barriers in K-loop. Wave-private staging.
__global__ __launch_bounds__(256, 4) void gemm_fold(const unsigned short* __restrict__ embB,
                                                    const unsigned short* __restrict__ rbT,
                                                    const int* __restrict__ ids,
                                                    const float* __restrict__ rel_att,
                                                    const float* __restrict__ relb,
                                                    float* __restrict__ gemmT) {
    __shared__ unsigned short bS[2][64 * 128];    // [buf][o_local*128 + i_local] (xor-swizzled)
    __shared__ unsigned int attH[32][32];         // [n][h] = half2(att[b=h], att[b=h+32])

    const int t = threadIdx.x;
    const int wv = t >> 6;
    const int ln = t & 63;
    const int q  = ln >> 4;     // quad 0..3
    const int lm = ln & 15;
    const int g  = blockIdx.x;
    const int o0 = (g & 7) * 64;                  // fastest -> XCD-aligned o slice
    const int m0 = ((g >> 3) & 63) * 64;
    const int nz = g >> 9;                        // n-half 0/1
    const int nbase = nz * 32;

    // async stage of one 64o x 128i bf16 tile; this wave's 4 chunks cover
    // rows [wv*16, wv*16+16) — wave-private producer/consumer.
    auto stage = [&](int s, int buf) {
        int ic = s >> 5, n = nbase + (s & 31);
#pragma unroll
        for (int j = 0; j < 4; j++) {
            int c   = wv * 4 + j;                 // chunk 0..15
            int r   = c * 4 + q;                  // o_local
            int c16 = (ln & 15) ^ (r & 15);       // logical i-chunk for this lane's slot
            const unsigned short* gp = rbT + (size_t)(n * 512 + o0 + r) * 512 + ic * 128 + c16 * 8;
            void* l = (char*)(&bS[buf][0]) + c * 1024;
            __builtin_amdgcn_global_load_lds((const __attribute__((address_space(1))) void*)gp,
                                             (__attribute__((address_space(3))) void*)l,
                                             16, 0, 0);
        }
    };

    stage(0, 0);
    stage(1, 1);

    // att tile packed to f16 pairs (b, b+32): 4 entries (8 gathers) per thread
#pragma unroll
    for (int k = 0; k < 4; k++) {
        int e = t + 256 * k;                      // 0..1023
        int n = e >> 5, h = e & 31;
        float a0 = rel_att[(size_t)ids[m0 + h] * 64 + nbase + n];
        float a1 = rel_att[(size_t)ids[m0 + h + 32] * 64 + nbase + n];
        __half2 hp = __floats2half2_rn(a0, a1);
        attH[n][h] = *(unsigned int*)&hp;
    }
    __syncthreads();                              // the ONLY block barrier before epilogue

    const f4 z = {0.f, 0.f, 0.f, 0.f};
    f4 acc[4] = {z, z, z, z};
    s8 embF[4][4];

    for (int s = 0; s < 128; s++) {
        int nl = s & 31;
        // tile s landed when only tile s+1's 4 loads remain outstanding
        if (s < 127) asm volatile("s_waitcnt vmcnt(4)" ::: "memory");
        else         asm volatile("s_waitcnt vmcnt(0)" ::: "memory");

        if (nl == 0) {
            // emb fragments for this i-chunk: register-resident across the n loop.
            int ic = s >> 5;
#pragma unroll
            for (int ks = 0; ks < 4; ks++)
#pragma unroll
                for (int ms = 0; ms < 4; ms++)
                    embF[ks][ms] = *(const s8*)(embB + (size_t)(m0 + ms * 16 + lm) * 512
                                                + ic * 128 + ks * 32 + q * 8);
        }

        const unsigned short* bp = &bS[s & 1][0];
        // A-fragments for this wave's 16 o-rows: 4 ds_read_b128
        s8 aF[4];
#pragma unroll
        for (int ks = 0; ks < 4; ks++) {
            int c16 = (ks * 4 + q) ^ lm;          // un-swizzle
            aF[ks] = *(const s8*)(bp + (wv * 16 + lm) * 128 + c16 * 8);
        }
        // att scales for this n: 2 x b32 -> 4 floats (pairs (ms0,ms2),(ms1,ms3))
        unsigned int p0 = attH[nl][lm], p1 = attH[nl][lm + 16];
        // fragments now in registers -> safe to overwrite this buffer (WAR resolved)
        asm volatile("s_waitcnt lgkmcnt(0)" ::: "memory");
        if (s + 2 < 128) stage(s + 2, s & 1);

        f4 an[4];
#pragma unroll
        for (int ms = 0; ms < 4; ms++)
            an[ms] = __builtin_amdgcn_mfma_f32_16x16x32_bf16(aF[0], embF[0][ms], z, 0, 0, 0);
#pragma unroll
        for (int ks = 1; ks < 4; ks++)
#pragma unroll
            for (int ms = 0; ms < 4; ms++)
                an[ms] = __builtin_amdgcn_mfma_f32_16x16x32_bf16(aF[ks], embF[ks][ms], an[ms], 0, 0, 0);
        float2 f0 = __half22float2(*(const __half2*)&p0);
        float2 f1 = __half22float2(*(const __half2*)&p1);
        acc[0] += f0.x * an[0];
        acc[1] += f1.x * an[1];
        acc[2] += f0.y * an[2];
        acc[3] += f1.y * an[3];
    }

    // bias fold: acc[ms] += sum_{n in half} att(n, b) * relb[nbase+n][o]
    // (relb f4 is wave-broadcast: o depends only on wv,q,r)
    const float* rbb = relb + (size_t)nbase * 512 + o0 + wv * 16 + q * 4;
#pragma unroll 4
    for (int n = 0; n < 32; n++) {
        unsigned int p0 = attH[n][lm], p1 = attH[n][lm + 16];
        float2 f0 = __half22float2(*(const __half2*)&p0);
        float2 f1 = __half22float2(*(const __half2*)&p1);
        f4 rb4 = *(const f4*)(rbb + (size_t)n * 512);
        acc[0] += f0.x * rb4;
        acc[1] += f1.x * rb4;
        acc[2] += f0.y * rb4;
        acc[3] += f1.y * rb4;
    }

    // transpose epilogue: acc (o-major fragments) -> [b][o] tile via LDS, then
    // coalesced stores. bS is dead; reuse as float[64][68] (17408B < 32KB).
    __syncthreads();                              // waves drift; protect bS reads
    float* T = (float*)&bS[0][0];
#pragma unroll
    for (int ms = 0; ms < 4; ms++)
#pragma unroll
        for (int r = 0; r < 4; r++)
            T[(ms * 16 + lm) * 68 + wv * 16 + q * 4 + r] = acc[ms][r];
    __syncthreads();
    float* gB = gemmT + (size_t)nz * 4096 * 512;
    const int mrow = t >> 2;
    const int oc = (t & 3) * 16;
    const float* Tr = T + mrow * 68 + oc;
    float* gp = gB + (size_t)(m0 + mrow) * 512 + o0 + oc;
#pragma unroll
    for (int j = 0; j < 4; j++)
        *(f4*)(gp + j * 4) = *(const f4*)(Tr + j * 4);
}

// LayerNorm over o (512) per b, [b][o] layout: pure-register, no LDS.
// 4 rows per block (64 lanes/row); grid 1024.  (R5-proven)
__global__ __launch_bounds__(256) void ln_kernel(const float* __restrict__ g0,
                                                 const float* __restrict__ g1,
                                                 float* __restrict__ out) {
    int t = threadIdx.x;
    int b = blockIdx.x * 4 + (t >> 6);
    int l = t & 63;
    const float* p0 = g0 + (size_t)b * 512 + l * 4;
    const float* p1 = g1 + (size_t)b * 512 + l * 4;
    f4 v[2];
    float s1 = 0.f, s2 = 0.f;
#pragma unroll
    for (int j = 0; j < 2; j++) {
        f4 a = *(const f4*)(p0 + j * 256);
        f4 c = *(const f4*)(p1 + j * 256);
        f4 w = a + c;
        v[j] = w;
        s1 += w[0] + w[1] + w[2] + w[3];
        s2 += w[0] * w[0] + w[1] * w[1] + w[2] * w[2] + w[3] * w[3];
    }
#pragma unroll
    for (int off = 32; off; off >>= 1) {
        s1 += __shfl_xor(s1, off, 64);
        s2 += __shfl_xor(s2, off, 64);
    }
    float mu = s1 * (1.f / 512.f);
    float var = s2 * (1.f / 512.f) - mu * mu;
    float rs = rsqrtf(var + 1e-5f);
    float* po = out + (size_t)b * 512 + l * 4;
#pragma unroll
    for (int j = 0; j < 2; j++) {
        f4 w = (v[j] - mu) * rs;
        *(f4*)(po + j * 256) = w;
    }
}

extern "C" void kernel_launch(void* const* d_in, const int* in_sizes, int n_in,
                              void* d_out, int out_size, void* d_ws, size_t ws_size,
                              hipStream_t stream) {
    (void)in_sizes; (void)n_in; (void)out_size; (void)ws_size;
    const float* emb      = (const float*)d_in[0];
    const int*   proj_ids = (const int*)d_in[1];
    const float* rel_att  = (const float*)d_in[2];
    const float* rel_base = (const float*)d_in[3];
    const float* rel_bias = (const float*)d_in[4];
    float* out = (float*)d_out;

    char* w = (char*)d_ws;
    unsigned short* embB  = (unsigned short*)(w + (1u << 20));
    unsigned short* rbT   = (unsigned short*)(w + 5u * (1u << 20));
    float*          gemmT = (float*)(w + 37u * (1u << 20));   // 2 slices of 8 MiB, [b][o]
    float*          g1    = gemmT + (size_t)4096 * 512;

    prep_kernel<<<dim3(1024 + 2048), dim3(256), 0, stream>>>(emb, embB, rel_base, rbT);
    gemm_fold<<<dim3(1024), dim3(256), 0, stream>>>(embB, rbT, proj_ids, rel_att, rel_bias, gemmT);
    ln_kernel<<<dim3(1024), dim3(256), 0, stream>>>(gemmT, g1, out);
}